// Round 3
// baseline (805.705 us; speedup 1.0000x reference)
//
#include <hip/hip_runtime.h>
#include <hip/hip_bf16.h>

// Shapes (fixed by the reference)
#define DIMD 1024
#define SEQL 4096
#define BATCH 4
#define NHEADS 16
#define DHEAD 64
#define KPROJ 64
#define MLPD 4096
#define NTOK (BATCH*SEQL)
#define EPSV 1e-5f
#define TPB 4   // tokens per block in k_attn_apply

using short8 = __attribute__((ext_vector_type(8))) short;
using f32x4  = __attribute__((ext_vector_type(4))) float;

__device__ __forceinline__ float wave_reduce_sum(float v) {
    #pragma unroll
    for (int off = 32; off > 0; off >>= 1) v += __shfl_down(v, off, 64);
    return v;
}

// async global->LDS DMA, 16 bytes per lane. lds base must be wave-uniform;
// HW scatters to base + laneID*16.
__device__ __forceinline__ void async_cp16(const unsigned short* g, unsigned short* l) {
    __builtin_amdgcn_global_load_lds(
        (const __attribute__((address_space(1))) unsigned int*)g,
        (__attribute__((address_space(3))) unsigned int*)l,
        16, 0, 0);
}

// ---------- K1: per-token LN1 stats (mu, rstd) ----------
__global__ __launch_bounds__(256) void k_stats1(const float* __restrict__ x,
                                                float* __restrict__ stats) {
    int t = blockIdx.x;
    const float4 x4 = *(const float4*)(x + (size_t)t*DIMD + threadIdx.x*4);
    float s  = x4.x + x4.y + x4.z + x4.w;
    float ss = x4.x*x4.x + x4.y*x4.y + x4.z*x4.z + x4.w*x4.w;
    s = wave_reduce_sum(s); ss = wave_reduce_sum(ss);
    __shared__ float rs[4], rss[4];
    int wave = threadIdx.x >> 6, lane = threadIdx.x & 63;
    if (lane == 0) { rs[wave] = s; rss[wave] = ss; }
    __syncthreads();
    if (threadIdx.x == 0) {
        float S1 = rs[0]+rs[1]+rs[2]+rs[3];
        float S2 = rss[0]+rss[1]+rss[2]+rss[3];
        float mu = S1 * (1.0f/DIMD);
        float var = S2 * (1.0f/DIMD) - mu*mu;
        stats[2*t]   = mu;
        stats[2*t+1] = rsqrtf(var + EPSV);
    }
}

// ---------- K2: xnsum[b][d] = sum_s LN1(x)[b,s,d]  (32-token chunks, atomics) ----------
__global__ __launch_bounds__(256) void k_xnsum(const float* __restrict__ x,
                                               const float* __restrict__ stats,
                                               const float* __restrict__ g1,
                                               const float* __restrict__ be1,
                                               float* __restrict__ xnsum) {
    int b = blockIdx.x >> 7, sc = blockIdx.x & 127;
    int d = threadIdx.x * 4;
    int t0 = b*SEQL + sc*32;
    float a0=0,a1=0,a2=0,a3=0;
    for (int s = 0; s < 32; s++) {
        int t = t0 + s;
        float mu = stats[2*t], rstd = stats[2*t+1];
        const float4 x4 = *(const float4*)(x + (size_t)t*DIMD + d);
        a0 += (x4.x-mu)*rstd; a1 += (x4.y-mu)*rstd;
        a2 += (x4.z-mu)*rstd; a3 += (x4.w-mu)*rstd;
    }
    const float4 g4 = *(const float4*)(g1 + d);
    const float4 b4 = *(const float4*)(be1 + d);
    atomicAdd(&xnsum[b*DIMD + d + 0], a0*g4.x + 32.0f*b4.x);
    atomicAdd(&xnsum[b*DIMD + d + 1], a1*g4.y + 32.0f*b4.y);
    atomicAdd(&xnsum[b*DIMD + d + 2], a2*g4.z + 32.0f*b4.z);
    atomicAdd(&xnsum[b*DIMD + d + 3], a3*g4.w + 32.0f*b4.w);
}

// ---------- K3: Esum[k] = sum_n E[n,k]; Fsum likewise ----------
__global__ __launch_bounds__(256) void k_efsum(const float* __restrict__ E,
                                               const float* __restrict__ Fm,
                                               float* __restrict__ Esum,
                                               float* __restrict__ Fsum) {
    int g = blockIdx.x;                 // 16 blocks, 256-row slabs
    int k = threadIdx.x & 63, seg = threadIdx.x >> 6;
    __shared__ float red[4][64];
    int n0 = g*256 + seg*64;
    float pe = 0, pf = 0;
    for (int i = 0; i < 64; i++) {
        pe += E [(size_t)(n0+i)*KPROJ + k];
        pf += Fm[(size_t)(n0+i)*KPROJ + k];
    }
    red[seg][k] = pe; __syncthreads();
    if (seg == 0) atomicAdd(&Esum[k], red[0][k]+red[1][k]+red[2][k]+red[3][k]);
    __syncthreads();
    red[seg][k] = pf; __syncthreads();
    if (seg == 0) atomicAdd(&Fsum[k], red[0][k]+red[1][k]+red[2][k]+red[3][k]);
}

// ---------- K4: Ksum[b][:] += xnsum[b][dchunk]@Wk[dchunk] ; same for Vsum ----------
__global__ __launch_bounds__(256) void k_kvsum(const float* __restrict__ xnsum,
                                               const float* __restrict__ Wk,
                                               const float* __restrict__ Wv,
                                               float* __restrict__ Ksum,
                                               float* __restrict__ Vsum) {
    int i = blockIdx.x;                 // 128 blocks: b(2b)|which(1b)|jc(2b)|dc(2b)
    int dc = i & 3, jc = (i >> 2) & 3, which = (i >> 4) & 1, b = i >> 5;
    const float* W = which ? Wv : Wk;
    float* outp = which ? Vsum : Ksum;
    int j = jc*256 + threadIdx.x;
    __shared__ float xs[256];
    xs[threadIdx.x] = xnsum[b*DIMD + dc*256 + threadIdx.x];
    __syncthreads();
    float acc = 0;
    #pragma unroll 8
    for (int dd = 0; dd < 256; dd++)
        acc += xs[dd] * W[(size_t)(dc*256 + dd)*DIMD + j];
    atomicAdd(&outp[b*DIMD + j], acc);
}

// ---------- K5a: Mt[b][h][d] = sum_j Wq[d][h*64+j]*Ksum[b][h*64+j] ----------
__global__ __launch_bounds__(256) void k_mt(const float* __restrict__ Wq,
                                            const float* __restrict__ Ksum,
                                            float* __restrict__ Mt) {
    int i = blockIdx.x;                 // 256 blocks: b(2b)|h(4b)|dc(2b)
    int dc = i & 3, h = (i >> 2) & 15, b = i >> 6;
    __shared__ float ks[DHEAD];
    if (threadIdx.x < DHEAD) ks[threadIdx.x] = Ksum[b*DIMD + h*DHEAD + threadIdx.x];
    __syncthreads();
    int d = dc*256 + threadIdx.x;
    float acc = 0;
    #pragma unroll 8
    for (int j = 0; j < DHEAD; j++) acc += Wq[(size_t)d*DIMD + h*DHEAD + j] * ks[j];
    Mt[((size_t)b*NHEADS + h)*DIMD + d] = acc;
}

// ---------- K5b: P[b][h][d] = sum_j Vsum[b][h*64+j]*Wo[h*64+j][d] ----------
__global__ __launch_bounds__(256) void k_p(const float* __restrict__ Wo,
                                           const float* __restrict__ Vsum,
                                           float* __restrict__ P) {
    int i = blockIdx.x;
    int dc = i & 3, h = (i >> 2) & 15, b = i >> 6;
    __shared__ float vs[DHEAD];
    if (threadIdx.x < DHEAD) vs[threadIdx.x] = Vsum[b*DIMD + h*DHEAD + threadIdx.x];
    __syncthreads();
    int d = dc*256 + threadIdx.x;
    float acc = 0;
    #pragma unroll 8
    for (int j = 0; j < DHEAD; j++) acc += vs[j] * Wo[(size_t)(h*DHEAD + j)*DIMD + d];
    P[((size_t)b*NHEADS + h)*DIMD + d] = acc;
}

// ---------- K6: fused per-token tail, TPB tokens per block ----------
__global__ __launch_bounds__(256) void k_attn_apply(
    const float* __restrict__ x, const float* __restrict__ stats,
    const float* __restrict__ Mt, const float* __restrict__ P,
    const float* __restrict__ Esum, const float* __restrict__ Fsum,
    const float* __restrict__ g1, const float* __restrict__ be1,
    const float* __restrict__ bo,
    const float* __restrict__ g2, const float* __restrict__ be2,
    float* __restrict__ y, __hip_bfloat16* __restrict__ xn2) {
    __shared__ float red[TPB][NHEADS][4];   // qk partials per wave
    __shared__ float w_s[TPB][NHEADS];
    __shared__ float red2[TPB][8];
    __shared__ float st2[TPB][2];
    const int t0 = blockIdx.x * TPB;
    const int b = t0 >> 12;                  // SEQ = 4096, TPB divides SEQ
    const int tid = threadIdx.x;
    const int wave = tid >> 6, lane = tid & 63;
    const int d4 = tid * 4;

    const float4 g14 = *(const float4*)(g1 + d4);
    const float4 b14 = *(const float4*)(be1 + d4);
    float4 xf[TPB], xn[TPB];
    #pragma unroll
    for (int t = 0; t < TPB; t++) {
        xf[t] = *(const float4*)(x + (size_t)(t0+t)*DIMD + d4);
        float mu = stats[2*(t0+t)], rstd = stats[2*(t0+t)+1];
        xn[t].x = (xf[t].x-mu)*rstd*g14.x + b14.x;
        xn[t].y = (xf[t].y-mu)*rstd*g14.y + b14.y;
        xn[t].z = (xf[t].z-mu)*rstd*g14.z + b14.z;
        xn[t].w = (xf[t].w-mu)*rstd*g14.w + b14.w;
    }
    // qk[t][h] = xn[t] . Mt[b][h][:]
    #pragma unroll
    for (int h = 0; h < NHEADS; h++) {
        const float4 m4 = *(const float4*)(Mt + ((size_t)b*NHEADS + h)*DIMD + d4);
        #pragma unroll
        for (int t = 0; t < TPB; t++) {
            float p = xn[t].x*m4.x + xn[t].y*m4.y + xn[t].z*m4.z + xn[t].w*m4.w;
            p = wave_reduce_sum(p);
            if (lane == 0) red[t][h][wave] = p;
        }
    }
    __syncthreads();
    // softmax weight per (t,h): w = sum_k softmax_k(scale*qk*Esum[k])*Fsum[k]
    {
        const float scale = 0.125f;          // DH^-0.5
        const float ek = Esum[lane], fk = Fsum[lane];
        for (int pi = wave; pi < TPB*NHEADS; pi += 4) {
            int t = pi >> 4, h = pi & 15;
            float qk = red[t][h][0]+red[t][h][1]+red[t][h][2]+red[t][h][3];
            float logit = qk * scale * ek;
            float m = logit;
            #pragma unroll
            for (int off = 32; off > 0; off >>= 1) m = fmaxf(m, __shfl_down(m, off, 64));
            m = __shfl(m, 0, 64);
            float e = expf(logit - m);
            float s1 = e, s2 = e * fk;
            #pragma unroll
            for (int off = 32; off > 0; off >>= 1) {
                s1 += __shfl_down(s1, off, 64);
                s2 += __shfl_down(s2, off, 64);
            }
            if (lane == 0) w_s[t][h] = s2 / s1;
        }
    }
    __syncthreads();
    // y = x + sum_h w*P + bo  (h outer: one P float4 live at a time)
    const float4 bo4 = *(const float4*)(bo + d4);
    #pragma unroll
    for (int t = 0; t < TPB; t++) {
        xf[t].x += bo4.x; xf[t].y += bo4.y; xf[t].z += bo4.z; xf[t].w += bo4.w;
    }
    #pragma unroll
    for (int h = 0; h < NHEADS; h++) {
        const float4 p4 = *(const float4*)(P + ((size_t)b*NHEADS + h)*DIMD + d4);
        #pragma unroll
        for (int t = 0; t < TPB; t++) {
            float wv = w_s[t][h];
            xf[t].x += wv*p4.x; xf[t].y += wv*p4.y;
            xf[t].z += wv*p4.z; xf[t].w += wv*p4.w;
        }
    }
    #pragma unroll
    for (int t = 0; t < TPB; t++) {
        *(float4*)(y + (size_t)(t0+t)*DIMD + d4) = xf[t];
        float s  = xf[t].x+xf[t].y+xf[t].z+xf[t].w;
        float ss = xf[t].x*xf[t].x+xf[t].y*xf[t].y+xf[t].z*xf[t].z+xf[t].w*xf[t].w;
        s = wave_reduce_sum(s); ss = wave_reduce_sum(ss);
        if (lane == 0) { red2[t][wave] = s; red2[t][4+wave] = ss; }
    }
    __syncthreads();
    if (tid < TPB) {
        float S1 = red2[tid][0]+red2[tid][1]+red2[tid][2]+red2[tid][3];
        float S2 = red2[tid][4]+red2[tid][5]+red2[tid][6]+red2[tid][7];
        float m2 = S1*(1.0f/DIMD);
        float v2 = S2*(1.0f/DIMD) - m2*m2;
        st2[tid][0] = m2; st2[tid][1] = rsqrtf(v2 + EPSV);
    }
    __syncthreads();
    const float4 g24 = *(const float4*)(g2 + d4);
    const float4 b24 = *(const float4*)(be2 + d4);
    #pragma unroll
    for (int t = 0; t < TPB; t++) {
        float mu2 = st2[t][0], rs2 = st2[t][1];
        union { __hip_bfloat16 h4[4]; uint2 v; } pk;
        pk.h4[0] = __float2bfloat16((xf[t].x-mu2)*rs2*g24.x + b24.x);
        pk.h4[1] = __float2bfloat16((xf[t].y-mu2)*rs2*g24.y + b24.y);
        pk.h4[2] = __float2bfloat16((xf[t].z-mu2)*rs2*g24.z + b24.z);
        pk.h4[3] = __float2bfloat16((xf[t].w-mu2)*rs2*g24.w + b24.w);
        *(uint2*)((char*)(xn2 + (size_t)(t0+t)*DIMD + d4)) = pk.v;
    }
}

// ---------- K7: transpose fp32 [R][C] -> bf16 [C][R] ----------
__global__ __launch_bounds__(256) void k_transpose_bf16(const float* __restrict__ src,
                                                        __hip_bfloat16* __restrict__ dst,
                                                        int R, int C) {
    __shared__ float tile[32][33];
    int c0 = blockIdx.x * 32, r0 = blockIdx.y * 32;
    int tx = threadIdx.x & 31, ty = threadIdx.x >> 5;   // ty: 0..7
    #pragma unroll
    for (int i = 0; i < 32; i += 8)
        tile[ty+i][tx] = src[(size_t)(r0+ty+i)*C + c0 + tx];
    __syncthreads();
    #pragma unroll
    for (int i = 0; i < 32; i += 8)
        dst[(size_t)(c0+ty+i)*R + r0 + tx] = __float2bfloat16(tile[tx][ty+i]);
}

// ---------- K8: 256x256-tile bf16 GEMM, 8-phase schedule (m201 template port) ----------
// C[M,N] = A[M,K] @ Bt[N,K]^T.  8 waves (2Mx4N), per-wave 128x64, mfma 16x16x32.
// BK=64; iteration = 2 K-tiles (buf0 = even kt, buf1 = odd kt); LDS = 2 x 32KB x2 = 128KB.
// Phase: {ds_reads || 1 half-tile stage} ; s_barrier ; lgkmcnt(0) ; sched_barrier(0)
// [rule-18 MFMA-hoist fence, the ONLY sched pin] ; setprio(1) ; 16 MFMA (kk-outer:
// 8 independent accumulators per kk-half, no dependent MFMA pairs) ; setprio(0) ;
// s_barrier.  s_barrier orders memory ops at MI-sched level; vmcnt asm keeps its
// "memory" clobber so stage-issues can't cross it (count semantics).
// Counted vmcnt(4) only at phases 4 & 8 (publishes one K-tile buffer; 4 loads
// stay in flight; drains to 0 only at last-iter P4).
// Hazard ledger (unchanged from r2, verified):
//  WAR: P1 stages A-buf1 (reads done P5/P7 prev iter); P3 stages B-buf0 (reads
//  done P2); P5 stages A-buf0 (reads done P1/P3); P7 stages B-buf1 (reads done
//  P5/P6) -- all >=1 barrier after the reads' lgkmcnt(0).
//  RAW: buf1(kt1) staged P7p,P8p,P1,P2, published P4 (vmcnt(4)+barrier), first
//  read P5; buf0(kt0+2) staged P3..P6, published P8, first read next-P1.
// LDS swizzle (zero-conflict, measured r1/r2): 16B-slot ^= (row&7); applied as
// inverse-permuted per-lane GLOBAL source + same XOR on ds_read (LDS dest linear).
// XCD swizzle (T1): bijective chunked remap, both grids divisible by 8.
// EPI==0: Cout = bf16, v = gelu(acc + bias)   (h = gelu(xn2@W1+b1))
// EPI==1: Cout = fp32, Cout += acc + bias     (out = y + h@W2 + b2)
template <int EPI>
__global__ __launch_bounds__(512, 2) void k_gemm256(
    const __hip_bfloat16* __restrict__ A, const __hip_bfloat16* __restrict__ Bt,
    const float* __restrict__ bias, void* __restrict__ Cout,
    int M, int N, int K) {
    __shared__ __align__(16) unsigned short As[2][256*64];
    __shared__ __align__(16) unsigned short Bs[2][256*64];

    // XCD-aware swizzle: hw round-robins blockIdx%8 across XCDs; remap so each
    // XCD gets a contiguous m-fast chunk (B-panel resident in its L2).
    const int nwg = gridDim.x;                        // 1024 or 256 (div by 8)
    const int wid = (blockIdx.x & 7) * (nwg >> 3) + (blockIdx.x >> 3);
    const int nbx = M >> 8;
    const int m0 = (wid % nbx) << 8;
    const int n0 = (wid / nbx) << 8;

    const int tid  = threadIdx.x;
    const int w    = tid >> 6, l = tid & 63;
    const int wm   = (w >> 2) * 128;         // wave grid: 2 (M) x 4 (N)
    const int wn   = (w & 3) * 64;
    const int quad = l >> 4, l15 = l & 15;

    f32x4 acc[8][4];
    #pragma unroll
    for (int i = 0; i < 8; i++)
        #pragma unroll
        for (int j = 0; j < 4; j++) acc[i][j] = 0;

    // ---- staging lane constants: per half-tile stage, wave w issue i covers
    // rows (h*128 + w*16 + i*8) + (l>>3), LDS slot l&7; source slot pre-XORed.
    const int lr = l >> 3;                   // 0..7 = row&7 of the staged row
    const int lc = ((l & 7) ^ lr) * 8;       // swizzled source col (ushorts)
    const unsigned short* Au = (const unsigned short*)A;
    const unsigned short* Bu = (const unsigned short*)Bt;
    const unsigned short* Asrc = Au + (size_t)(m0 + w*16 + lr)*K + lc;
    const unsigned short* Bsrc = Bu + (size_t)(n0 + w*16 + lr)*K + lc;

#define STAGE_A(d, h, kt) do { \
    async_cp16(Asrc + (size_t)((h)*128)*K     + (kt)*64, &As[d][((h)*128 + w*16)*64]); \
    async_cp16(Asrc + (size_t)((h)*128 + 8)*K + (kt)*64, &As[d][((h)*128 + w*16 + 8)*64]); \
} while (0)
#define STAGE_B(d, h, kt) do { \
    async_cp16(Bsrc + (size_t)((h)*128)*K     + (kt)*64, &Bs[d][((h)*128 + w*16)*64]); \
    async_cp16(Bsrc + (size_t)((h)*128 + 8)*K + (kt)*64, &Bs[d][((h)*128 + w*16 + 8)*64]); \
} while (0)

    // ---- fragment read addressing: row = (wm|wn) + frag*16 + l15;
    // slot = (kk*4+quad) ^ (row&7) with row&7 == l15&7.
    const int sl0 = ((quad)     ^ (l15 & 7)) * 8;    // kk=0
    const int sl1 = ((4 + quad) ^ (l15 & 7)) * 8;    // kk=1
    const int arow = (wm + l15) * 64;
    const int brow = (wn + l15) * 64;

    short8 af[8], bf0[4], bf1[4];

#define RD_AF(d, s) do { \
    _Pragma("unroll") \
    for (int mf = 0; mf < 4; mf++) { \
        af[mf*2+0] = *(const short8*)&As[d][arow + ((s)*4+mf)*1024 + sl0]; \
        af[mf*2+1] = *(const short8*)&As[d][arow + ((s)*4+mf)*1024 + sl1]; \
    } } while (0)
#define RD_BF(dst, d, s) do { \
    _Pragma("unroll") \
    for (int nf = 0; nf < 2; nf++) { \
        dst[nf*2+0] = *(const short8*)&Bs[d][brow + ((s)*2+nf)*1024 + sl0]; \
        dst[nf*2+1] = *(const short8*)&Bs[d][brow + ((s)*2+nf)*1024 + sl1]; \
    } } while (0)

// kk-outer: 8 independent accs per kk-half; per-acc order still kk0 then kk1
// (bitwise-identical accumulation vs r2).
#define QPH(MB, NB, BF) do { \
    _Pragma("unroll") \
    for (int kk = 0; kk < 2; kk++) \
        _Pragma("unroll") \
        for (int mf = 0; mf < 4; mf++) \
            _Pragma("unroll") \
            for (int nf = 0; nf < 2; nf++) \
                acc[(MB)+mf][(NB)+nf] = __builtin_amdgcn_mfma_f32_16x16x32_bf16(af[mf*2+kk], BF[nf*2+kk], acc[(MB)+mf][(NB)+nf], 0, 0, 0); \
    } while (0)

#define PH_TAIL(MB, NB, BF) do { \
    __builtin_amdgcn_s_barrier(); \
    asm volatile("s_waitcnt lgkmcnt(0)"); \
    __builtin_amdgcn_sched_barrier(0); \
    __builtin_amdgcn_s_setprio(1); \
    QPH(MB, NB, BF); \
    __builtin_amdgcn_s_setprio(0); \
    __builtin_amdgcn_s_barrier(); \
} while (0)

    const int nit = K >> 7;                  // K / 128 (>= 2 for all our shapes)

    // ---- prologue: buf0 <- kt0=0 (all 4 halves), buf1 <- B halves of kt=1.
    STAGE_B(0, 0, 0); STAGE_B(0, 1, 0); STAGE_A(0, 0, 0); STAGE_A(0, 1, 0);
    STAGE_B(1, 0, 1); STAGE_B(1, 1, 1);
    asm volatile("s_waitcnt vmcnt(4)" ::: "memory");   // buf0 resident
    __builtin_amdgcn_s_barrier();

    for (int it = 0; it < nit; ++it) {
        const int kt0 = it*2, kt1 = it*2 + 1;
        const bool more = (it + 1 < nit);
        // ---- P1: reads A0,B0 (buf0); stage A-h0 -> buf1(kt1); MFMA Q00(T0)
        RD_AF(0, 0); RD_BF(bf0, 0, 0);
        STAGE_A(1, 0, kt1);
        PH_TAIL(0, 0, bf0);
        // ---- P2: reads B1 (buf0); stage A-h1 -> buf1(kt1); MFMA Q01(T0)
        RD_BF(bf1, 0, 1);
        STAGE_A(1, 1, kt1);
        PH_TAIL(0, 2, bf1);
        // ---- P3: reads A1 (buf0); stage B-h0 -> buf0(kt0+2); MFMA Q11(T0)
        RD_AF(0, 1);
        if (more) STAGE_B(0, 0, kt0 + 2);
        PH_TAIL(4, 2, bf1);
        // ---- P4: stage B-h1 -> buf0(kt0+2); vmcnt publishes buf1(kt1); MFMA Q10(T0)
        if (more) {
            STAGE_B(0, 1, kt0 + 2);
            asm volatile("s_waitcnt vmcnt(4)" ::: "memory");
        } else {
            asm volatile("s_waitcnt vmcnt(0)" ::: "memory");
        }
        PH_TAIL(4, 0, bf0);
        // ---- P5: reads A0,B0 (buf1); stage A-h0 -> buf0(kt0+2); MFMA Q00(T1)
        RD_AF(1, 0); RD_BF(bf0, 1, 0);
        if (more) STAGE_A(0, 0, kt0 + 2);
        PH_TAIL(0, 0, bf0);
        // ---- P6: reads B1 (buf1); stage A-h1 -> buf0(kt0+2); MFMA Q01(T1)
        RD_BF(bf1, 1, 1);
        if (more) STAGE_A(0, 1, kt0 + 2);
        PH_TAIL(0, 2, bf1);
        // ---- P7: reads A1 (buf1); stage B-h0 -> buf1(kt1+2); MFMA Q11(T1)
        RD_AF(1, 1);
        if (more) STAGE_B(1, 0, kt1 + 2);
        PH_TAIL(4, 2, bf1);
        // ---- P8: stage B-h1 -> buf1(kt1+2); vmcnt publishes buf0(kt0+2); MFMA Q10(T1)
        if (more) {
            STAGE_B(1, 1, kt1 + 2);
            asm volatile("s_waitcnt vmcnt(4)" ::: "memory");
        }
        PH_TAIL(4, 0, bf0);
    }

    // epilogue: C/D layout row = quad*4 + r, col = l15 (verified)
    #pragma unroll
    for (int nf = 0; nf < 4; nf++) {
        const int col = n0 + wn + nf*16 + l15;
        const float bv = bias[col];
        #pragma unroll
        for (int mf = 0; mf < 8; mf++) {
            #pragma unroll
            for (int r = 0; r < 4; r++) {
                const int row = m0 + wm + mf*16 + quad*4 + r;
                float v = acc[mf][nf][r] + bv;
                if (EPI == 0) {
                    // tanh-form gelu (|err| < 3e-3, threshold is 311 abs)
                    float u = 0.7978845608f * (v + 0.044715f * v * v * v);
                    float e = __expf(2.0f * u);
                    float th = 1.0f - 2.0f / (e + 1.0f);   // safe at e=inf/0
                    float gl = 0.5f * v * (1.0f + th);
                    ((__hip_bfloat16*)Cout)[(size_t)row*N + col] = __float2bfloat16(gl);
                } else {
                    ((float*)Cout)[(size_t)row*N + col] += v;
                }
            }
        }
    }
#undef STAGE_A
#undef STAGE_B
#undef RD_AF
#undef RD_BF
#undef QPH
#undef PH_TAIL
}

extern "C" void kernel_launch(void* const* d_in, const int* in_sizes, int n_in,
                              void* d_out, int out_size, void* d_ws, size_t ws_size,
                              hipStream_t stream) {
    const float* x   = (const float*)d_in[0];
    const float* Wq  = (const float*)d_in[1];
    const float* Wk  = (const float*)d_in[2];
    const float* Wv  = (const float*)d_in[3];
    const float* E   = (const float*)d_in[4];
    const float* Fm  = (const float*)d_in[5];
    const float* Wo  = (const float*)d_in[6];
    const float* bo  = (const float*)d_in[7];
    const float* g1  = (const float*)d_in[8];
    const float* be1 = (const float*)d_in[9];
    const float* g2  = (const float*)d_in[10];
    const float* be2 = (const float*)d_in[11];
    const float* W1  = (const float*)d_in[12];
    const float* bb1 = (const float*)d_in[13];
    const float* W2  = (const float*)d_in[14];
    const float* bb2 = (const float*)d_in[15];
    float* outp = (float*)d_out;

    char* ws = (char*)d_ws;
    size_t o = 0;
    auto alloc = [&](size_t bytes) -> char* {
        char* r = ws + o;
        o = (o + bytes + 255) & ~(size_t)255;
        return r;
    };
    float* xnsum = (float*)alloc((size_t)BATCH*DIMD*4);
    float* Esum  = (float*)alloc(KPROJ*4);
    float* Fsum  = (float*)alloc(KPROJ*4);
    float* stats = (float*)alloc((size_t)NTOK*2*4);
    float* Ksum  = (float*)alloc((size_t)BATCH*DIMD*4);
    float* Vsum  = (float*)alloc((size_t)BATCH*DIMD*4);
    float* Mt    = (float*)alloc((size_t)BATCH*NHEADS*DIMD*4);
    float* P     = (float*)alloc((size_t)BATCH*NHEADS*DIMD*4);
    __hip_bfloat16* xn2  = (__hip_bfloat16*)alloc((size_t)NTOK*DIMD*2);
    __hip_bfloat16* W1T  = (__hip_bfloat16*)alloc((size_t)DIMD*MLPD*2);
    __hip_bfloat16* W2T  = (__hip_bfloat16*)alloc((size_t)MLPD*DIMD*2);
    __hip_bfloat16* hbuf = (__hip_bfloat16*)alloc((size_t)NTOK*MLPD*2);

    hipMemsetAsync(xnsum, 0, (size_t)BATCH*DIMD*4, stream);
    hipMemsetAsync(Esum, 0, KPROJ*4, stream);
    hipMemsetAsync(Fsum, 0, KPROJ*4, stream);
    hipMemsetAsync(Ksum, 0, (size_t)BATCH*DIMD*4, stream);
    hipMemsetAsync(Vsum, 0, (size_t)BATCH*DIMD*4, stream);

    k_stats1<<<dim3(NTOK), dim3(256), 0, stream>>>(x, stats);
    k_xnsum<<<dim3(BATCH*128), dim3(256), 0, stream>>>(x, stats, g1, be1, xnsum);
    k_efsum<<<dim3(16), dim3(256), 0, stream>>>(E, Fm, Esum, Fsum);
    k_kvsum<<<dim3(128), dim3(256), 0, stream>>>(xnsum, Wk, Wv, Ksum, Vsum);
    k_mt<<<dim3(256), dim3(256), 0, stream>>>(Wq, Ksum, Mt);
    k_p<<<dim3(256), dim3(256), 0, stream>>>(Wo, Vsum, P);
    k_attn_apply<<<dim3(NTOK/TPB), dim3(256), 0, stream>>>(
        x, stats, Mt, P, Esum, Fsum, g1, be1, bo, g2, be2, outp, xn2);
    // W1: [K=1024][N=4096] -> W1T [4096][1024]; W2: [4096][1024] -> W2T [1024][4096]
    k_transpose_bf16<<<dim3(MLPD/32, DIMD/32), dim3(256), 0, stream>>>(W1, W1T, DIMD, MLPD);
    k_transpose_bf16<<<dim3(DIMD/32, MLPD/32), dim3(256), 0, stream>>>(W2, W2T, MLPD, DIMD);
    // GEMM1: h = gelu(xn2 @ W1 + b1)   M=16384 N=4096 K=1024  (64x16 = 1024 blocks)
    k_gemm256<0><<<dim3((NTOK/256)*(MLPD/256)), dim3(512), 0, stream>>>(
        xn2, W1T, bb1, (void*)hbuf, NTOK, MLPD, DIMD);
    // GEMM2: out = y + h @ W2 + b2     M=16384 N=1024 K=4096  (64x4 = 256 blocks)
    k_gemm256<1><<<dim3((NTOK/256)*(DIMD/256)), dim3(512), 0, stream>>>(
        hbuf, W2T, bb2, (void*)outp, NTOK, DIMD, MLPD);
}

// Round 4
// 753.895 us; speedup vs baseline: 1.0687x; 1.0687x over previous
//
#include <hip/hip_runtime.h>
#include <hip/hip_bf16.h>

// Shapes (fixed by the reference)
#define DIMD 1024
#define SEQL 4096
#define BATCH 4
#define NHEADS 16
#define DHEAD 64
#define KPROJ 64
#define MLPD 4096
#define NTOK (BATCH*SEQL)
#define EPSV 1e-5f
#define TPB 4   // tokens per block in k_attn_apply

using short8 = __attribute__((ext_vector_type(8))) short;
using f32x4  = __attribute__((ext_vector_type(4))) float;

__device__ __forceinline__ float wave_reduce_sum(float v) {
    #pragma unroll
    for (int off = 32; off > 0; off >>= 1) v += __shfl_down(v, off, 64);
    return v;
}

// async global->LDS DMA, 16 bytes per lane. lds base must be wave-uniform;
// HW scatters to base + laneID*16.
__device__ __forceinline__ void async_cp16(const unsigned short* g, unsigned short* l) {
    __builtin_amdgcn_global_load_lds(
        (const __attribute__((address_space(1))) unsigned int*)g,
        (__attribute__((address_space(3))) unsigned int*)l,
        16, 0, 0);
}

// ---------- K1: fused LN1 stats + xnsum. 512 blocks x 32 tokens.
// Wave w of 4 handles tokens w,w+4,...,w+28. Per token: wave-reduce mu/rstd,
// write stats, accumulate per-lane (x-mu)*rstd into acc[16 d-positions].
// Then cross-wave LDS reduce and one atomicAdd pass (g1/be1 applied here). ----------
__global__ __launch_bounds__(256) void k_ln1sum(const float* __restrict__ x,
                                                const float* __restrict__ g1,
                                                const float* __restrict__ be1,
                                                float* __restrict__ stats,
                                                float* __restrict__ xnsum) {
    const int b = blockIdx.x >> 7, sc = blockIdx.x & 127;
    const int t0 = b*SEQL + sc*32;
    const int wave = threadIdx.x >> 6, lane = threadIdx.x & 63;
    __shared__ float4 red[4][256];           // [wave][float4-slot]
    float4 a4[4];
    #pragma unroll
    for (int j = 0; j < 4; j++) a4[j] = make_float4(0,0,0,0);

    for (int i = 0; i < 8; i++) {
        const int t = t0 + wave + i*4;
        const float4* xr = (const float4*)(x + (size_t)t*DIMD);
        float4 v[4];
        float s = 0, ss = 0;
        #pragma unroll
        for (int j = 0; j < 4; j++) {
            v[j] = xr[j*64 + lane];
            s  += v[j].x + v[j].y + v[j].z + v[j].w;
            ss += v[j].x*v[j].x + v[j].y*v[j].y + v[j].z*v[j].z + v[j].w*v[j].w;
        }
        s = wave_reduce_sum(s); ss = wave_reduce_sum(ss);
        s = __shfl(s, 0, 64); ss = __shfl(ss, 0, 64);
        float mu = s * (1.0f/DIMD);
        float var = ss * (1.0f/DIMD) - mu*mu;
        float rstd = rsqrtf(var + EPSV);
        if (lane == 0) { stats[2*t] = mu; stats[2*t+1] = rstd; }
        #pragma unroll
        for (int j = 0; j < 4; j++) {
            a4[j].x += (v[j].x-mu)*rstd; a4[j].y += (v[j].y-mu)*rstd;
            a4[j].z += (v[j].z-mu)*rstd; a4[j].w += (v[j].w-mu)*rstd;
        }
    }
    #pragma unroll
    for (int j = 0; j < 4; j++) red[wave][j*64 + lane] = a4[j];
    __syncthreads();
    // reducer: thread t handles float4 slot t -> d = (t>>6)*256 + (t&63)*4
    const int slot = threadIdx.x;
    const int d = (slot >> 6)*256 + (slot & 63)*4;
    float4 r0 = red[0][slot], r1 = red[1][slot], r2 = red[2][slot], r3 = red[3][slot];
    const float4 g4 = *(const float4*)(g1 + d);
    const float4 b4 = *(const float4*)(be1 + d);
    atomicAdd(&xnsum[b*DIMD + d + 0], (r0.x+r1.x+r2.x+r3.x)*g4.x + 32.0f*b4.x);
    atomicAdd(&xnsum[b*DIMD + d + 1], (r0.y+r1.y+r2.y+r3.y)*g4.y + 32.0f*b4.y);
    atomicAdd(&xnsum[b*DIMD + d + 2], (r0.z+r1.z+r2.z+r3.z)*g4.z + 32.0f*b4.z);
    atomicAdd(&xnsum[b*DIMD + d + 3], (r0.w+r1.w+r2.w+r3.w)*g4.w + 32.0f*b4.w);
}

// ---------- K3: Esum[k] = sum_n E[n,k]; Fsum likewise. 256 blocks x 16 rows. ----------
__global__ __launch_bounds__(256) void k_efsum(const float* __restrict__ E,
                                               const float* __restrict__ Fm,
                                               float* __restrict__ Esum,
                                               float* __restrict__ Fsum) {
    int g = blockIdx.x;
    int k = threadIdx.x & 63, seg = threadIdx.x >> 6;
    __shared__ float red[4][64];
    int n0 = g*16 + seg*4;
    float pe = 0, pf = 0;
    #pragma unroll
    for (int i = 0; i < 4; i++) {
        pe += E [(size_t)(n0+i)*KPROJ + k];
        pf += Fm[(size_t)(n0+i)*KPROJ + k];
    }
    red[seg][k] = pe; __syncthreads();
    if (seg == 0) atomicAdd(&Esum[k], red[0][k]+red[1][k]+red[2][k]+red[3][k]);
    __syncthreads();
    red[seg][k] = pf; __syncthreads();
    if (seg == 0) atomicAdd(&Fsum[k], red[0][k]+red[1][k]+red[2][k]+red[3][k]);
}

// ---------- K4: Ksum/Vsum = xnsum @ Wk/Wv. 512 blocks: which(2)|jc(16)|dc(16).
// Each W 64x64 tile read exactly once; all 4 batches per block. ----------
__global__ __launch_bounds__(256) void k_kvsum(const float* __restrict__ xnsum,
                                               const float* __restrict__ Wk,
                                               const float* __restrict__ Wv,
                                               float* __restrict__ Ksum,
                                               float* __restrict__ Vsum) {
    int i = blockIdx.x;
    int dc = i & 15, jc = (i >> 4) & 15, which = i >> 8;
    const float* W = which ? Wv : Wk;
    float* outp = which ? Vsum : Ksum;
    const int j = threadIdx.x & 63, ib = threadIdx.x >> 6;
    __shared__ float xs[4][64];
    __shared__ float red[4][4][64];
    xs[ib][j] = xnsum[ib*DIMD + dc*64 + j];   // ib doubles as batch idx here
    __syncthreads();
    float a0=0,a1=0,a2=0,a3=0;
    #pragma unroll
    for (int q = 0; q < 16; q++) {
        int dd = ib*16 + q;
        float wv = W[(size_t)(dc*64 + dd)*DIMD + jc*64 + j];
        a0 += xs[0][dd]*wv; a1 += xs[1][dd]*wv;
        a2 += xs[2][dd]*wv; a3 += xs[3][dd]*wv;
    }
    red[ib][0][j]=a0; red[ib][1][j]=a1; red[ib][2][j]=a2; red[ib][3][j]=a3;
    __syncthreads();
    if (ib == 0) {
        #pragma unroll
        for (int b = 0; b < 4; b++)
            atomicAdd(&outp[b*DIMD + jc*64 + j],
                      red[0][b][j]+red[1][b][j]+red[2][b][j]+red[3][b][j]);
    }
}

// ---------- K5a: Mt[b][h][d] = sum_j Wq[d][h*64+j]*Ksum[b][h*64+j].
// 128 blocks: h(16)|dc(8 of 128). Wq tile LDS-staged (coalesced), read once. ----------
__global__ __launch_bounds__(256) void k_mt(const float* __restrict__ Wq,
                                            const float* __restrict__ Ksum,
                                            float* __restrict__ Mt) {
    int i = blockIdx.x;
    int dc = i & 7, h = i >> 3;
    __shared__ float Wqs[128][65];
    __shared__ float ks[4][64];
    const int j = threadIdx.x & 63, seg = threadIdx.x >> 6;
    if (threadIdx.x < 256) ks[seg][j] = Ksum[seg*DIMD + h*DHEAD + j];
    #pragma unroll 8
    for (int it = 0; it < 32; it++) {
        int rl = it*4 + seg;
        Wqs[rl][j] = Wq[(size_t)(dc*128 + rl)*DIMD + h*DHEAD + j];
    }
    __syncthreads();
    const int dl = threadIdx.x & 127, bh = threadIdx.x >> 7;
    #pragma unroll
    for (int bi = 0; bi < 2; bi++) {
        int b = bh*2 + bi;
        float acc = 0;
        #pragma unroll 8
        for (int jj = 0; jj < DHEAD; jj++) acc += Wqs[dl][jj] * ks[b][jj];
        Mt[((size_t)b*NHEADS + h)*DIMD + dc*128 + dl] = acc;
    }
}

// ---------- K5b: P[b][h][d] = sum_j Vsum[b][h*64+j]*Wo[h*64+j][d].
// 256 blocks: h(16)|dc(16 of 64). Wo coalesced, read once; all b per block. ----------
__global__ __launch_bounds__(256) void k_p(const float* __restrict__ Wo,
                                           const float* __restrict__ Vsum,
                                           float* __restrict__ P) {
    int i = blockIdx.x;
    int dc = i & 15, h = i >> 4;
    __shared__ float vs[4][64];
    const int d = threadIdx.x & 63, b = threadIdx.x >> 6;
    vs[b][d] = Vsum[b*DIMD + h*DHEAD + d];
    __syncthreads();
    float acc = 0;
    #pragma unroll 8
    for (int j = 0; j < DHEAD; j++)
        acc += vs[b][j] * Wo[(size_t)(h*DHEAD + j)*DIMD + dc*64 + d];
    P[((size_t)b*NHEADS + h)*DIMD + dc*64 + d] = acc;
}

// ---------- K6: fused per-token tail, TPB tokens per block ----------
__global__ __launch_bounds__(256) void k_attn_apply(
    const float* __restrict__ x, const float* __restrict__ stats,
    const float* __restrict__ Mt, const float* __restrict__ P,
    const float* __restrict__ Esum, const float* __restrict__ Fsum,
    const float* __restrict__ g1, const float* __restrict__ be1,
    const float* __restrict__ bo,
    const float* __restrict__ g2, const float* __restrict__ be2,
    float* __restrict__ y, __hip_bfloat16* __restrict__ xn2) {
    __shared__ float red[TPB][NHEADS][4];   // qk partials per wave
    __shared__ float w_s[TPB][NHEADS];
    __shared__ float red2[TPB][8];
    __shared__ float st2[TPB][2];
    const int t0 = blockIdx.x * TPB;
    const int b = t0 >> 12;                  // SEQ = 4096, TPB divides SEQ
    const int tid = threadIdx.x;
    const int wave = tid >> 6, lane = tid & 63;
    const int d4 = tid * 4;

    const float4 g14 = *(const float4*)(g1 + d4);
    const float4 b14 = *(const float4*)(be1 + d4);
    float4 xf[TPB], xn[TPB];
    #pragma unroll
    for (int t = 0; t < TPB; t++) {
        xf[t] = *(const float4*)(x + (size_t)(t0+t)*DIMD + d4);
        float mu = stats[2*(t0+t)], rstd = stats[2*(t0+t)+1];
        xn[t].x = (xf[t].x-mu)*rstd*g14.x + b14.x;
        xn[t].y = (xf[t].y-mu)*rstd*g14.y + b14.y;
        xn[t].z = (xf[t].z-mu)*rstd*g14.z + b14.z;
        xn[t].w = (xf[t].w-mu)*rstd*g14.w + b14.w;
    }
    // qk[t][h] = xn[t] . Mt[b][h][:]
    #pragma unroll
    for (int h = 0; h < NHEADS; h++) {
        const float4 m4 = *(const float4*)(Mt + ((size_t)b*NHEADS + h)*DIMD + d4);
        #pragma unroll
        for (int t = 0; t < TPB; t++) {
            float p = xn[t].x*m4.x + xn[t].y*m4.y + xn[t].z*m4.z + xn[t].w*m4.w;
            p = wave_reduce_sum(p);
            if (lane == 0) red[t][h][wave] = p;
        }
    }
    __syncthreads();
    // softmax weight per (t,h): w = sum_k softmax_k(scale*qk*Esum[k])*Fsum[k]
    {
        const float scale = 0.125f;          // DH^-0.5
        const float ek = Esum[lane], fk = Fsum[lane];
        for (int pi = wave; pi < TPB*NHEADS; pi += 4) {
            int t = pi >> 4, h = pi & 15;
            float qk = red[t][h][0]+red[t][h][1]+red[t][h][2]+red[t][h][3];
            float logit = qk * scale * ek;
            float m = logit;
            #pragma unroll
            for (int off = 32; off > 0; off >>= 1) m = fmaxf(m, __shfl_down(m, off, 64));
            m = __shfl(m, 0, 64);
            float e = expf(logit - m);
            float s1 = e, s2 = e * fk;
            #pragma unroll
            for (int off = 32; off > 0; off >>= 1) {
                s1 += __shfl_down(s1, off, 64);
                s2 += __shfl_down(s2, off, 64);
            }
            if (lane == 0) w_s[t][h] = s2 / s1;
        }
    }
    __syncthreads();
    // y = x + sum_h w*P + bo  (h outer: one P float4 live at a time)
    const float4 bo4 = *(const float4*)(bo + d4);
    #pragma unroll
    for (int t = 0; t < TPB; t++) {
        xf[t].x += bo4.x; xf[t].y += bo4.y; xf[t].z += bo4.z; xf[t].w += bo4.w;
    }
    #pragma unroll
    for (int h = 0; h < NHEADS; h++) {
        const float4 p4 = *(const float4*)(P + ((size_t)b*NHEADS + h)*DIMD + d4);
        #pragma unroll
        for (int t = 0; t < TPB; t++) {
            float wv = w_s[t][h];
            xf[t].x += wv*p4.x; xf[t].y += wv*p4.y;
            xf[t].z += wv*p4.z; xf[t].w += wv*p4.w;
        }
    }
    #pragma unroll
    for (int t = 0; t < TPB; t++) {
        *(float4*)(y + (size_t)(t0+t)*DIMD + d4) = xf[t];
        float s  = xf[t].x+xf[t].y+xf[t].z+xf[t].w;
        float ss = xf[t].x*xf[t].x+xf[t].y*xf[t].y+xf[t].z*xf[t].z+xf[t].w*xf[t].w;
        s = wave_reduce_sum(s); ss = wave_reduce_sum(ss);
        if (lane == 0) { red2[t][wave] = s; red2[t][4+wave] = ss; }
    }
    __syncthreads();
    if (tid < TPB) {
        float S1 = red2[tid][0]+red2[tid][1]+red2[tid][2]+red2[tid][3];
        float S2 = red2[tid][4]+red2[tid][5]+red2[tid][6]+red2[tid][7];
        float m2 = S1*(1.0f/DIMD);
        float v2 = S2*(1.0f/DIMD) - m2*m2;
        st2[tid][0] = m2; st2[tid][1] = rsqrtf(v2 + EPSV);
    }
    __syncthreads();
    const float4 g24 = *(const float4*)(g2 + d4);
    const float4 b24 = *(const float4*)(be2 + d4);
    #pragma unroll
    for (int t = 0; t < TPB; t++) {
        float mu2 = st2[t][0], rs2 = st2[t][1];
        union { __hip_bfloat16 h4[4]; uint2 v; } pk;
        pk.h4[0] = __float2bfloat16((xf[t].x-mu2)*rs2*g24.x + b24.x);
        pk.h4[1] = __float2bfloat16((xf[t].y-mu2)*rs2*g24.y + b24.y);
        pk.h4[2] = __float2bfloat16((xf[t].z-mu2)*rs2*g24.z + b24.z);
        pk.h4[3] = __float2bfloat16((xf[t].w-mu2)*rs2*g24.w + b24.w);
        *(uint2*)((char*)(xn2 + (size_t)(t0+t)*DIMD + d4)) = pk.v;
    }
}

// ---------- K7: transpose fp32 [R][C] -> bf16 [C][R] ----------
__global__ __launch_bounds__(256) void k_transpose_bf16(const float* __restrict__ src,
                                                        __hip_bfloat16* __restrict__ dst,
                                                        int R, int C) {
    __shared__ float tile[32][33];
    int c0 = blockIdx.x * 32, r0 = blockIdx.y * 32;
    int tx = threadIdx.x & 31, ty = threadIdx.x >> 5;   // ty: 0..7
    #pragma unroll
    for (int i = 0; i < 32; i += 8)
        tile[ty+i][tx] = src[(size_t)(r0+ty+i)*C + c0 + tx];
    __syncthreads();
    #pragma unroll
    for (int i = 0; i < 32; i += 8)
        dst[(size_t)(c0+ty+i)*R + r0 + tx] = __float2bfloat16(tile[tx][ty+i]);
}

// ---------- K8: 256x256-tile bf16 GEMM, 8-phase schedule (as r2/r3; main loop
// frozen for A/B comparability). Epilogue: gelu divide -> rcp (EPI==0). ----------
template <int EPI>
__global__ __launch_bounds__(512, 2) void k_gemm256(
    const __hip_bfloat16* __restrict__ A, const __hip_bfloat16* __restrict__ Bt,
    const float* __restrict__ bias, void* __restrict__ Cout,
    int M, int N, int K) {
    __shared__ __align__(16) unsigned short As[2][256*64];
    __shared__ __align__(16) unsigned short Bs[2][256*64];

    const int nbx = M >> 8;
    const int m0 = (blockIdx.x % nbx) << 8;
    const int n0 = (blockIdx.x / nbx) << 8;

    const int tid  = threadIdx.x;
    const int w    = tid >> 6, l = tid & 63;
    const int wm   = (w >> 2) * 128;         // wave grid: 2 (M) x 4 (N)
    const int wn   = (w & 3) * 64;
    const int quad = l >> 4, l15 = l & 15;

    f32x4 acc[8][4];
    #pragma unroll
    for (int i = 0; i < 8; i++)
        #pragma unroll
        for (int j = 0; j < 4; j++) acc[i][j] = 0;

    const int lr = l >> 3;                   // 0..7 = row&7 of the staged row
    const int lc = ((l & 7) ^ lr) * 8;       // swizzled source col (ushorts)
    const unsigned short* Au = (const unsigned short*)A;
    const unsigned short* Bu = (const unsigned short*)Bt;
    const unsigned short* Asrc = Au + (size_t)(m0 + w*16 + lr)*K + lc;
    const unsigned short* Bsrc = Bu + (size_t)(n0 + w*16 + lr)*K + lc;

#define STAGE_A(d, h, kt) do { \
    async_cp16(Asrc + (size_t)((h)*128)*K     + (kt)*64, &As[d][((h)*128 + w*16)*64]); \
    async_cp16(Asrc + (size_t)((h)*128 + 8)*K + (kt)*64, &As[d][((h)*128 + w*16 + 8)*64]); \
} while (0)
#define STAGE_B(d, h, kt) do { \
    async_cp16(Bsrc + (size_t)((h)*128)*K     + (kt)*64, &Bs[d][((h)*128 + w*16)*64]); \
    async_cp16(Bsrc + (size_t)((h)*128 + 8)*K + (kt)*64, &Bs[d][((h)*128 + w*16 + 8)*64]); \
} while (0)

    const int sl0 = ((quad)     ^ (l15 & 7)) * 8;    // kk=0
    const int sl1 = ((4 + quad) ^ (l15 & 7)) * 8;    // kk=1
    const int arow = (wm + l15) * 64;
    const int brow = (wn + l15) * 64;

    short8 af[8], bf0[4], bf1[4];

#define RD_AF(d, s) do { \
    _Pragma("unroll") \
    for (int mf = 0; mf < 4; mf++) { \
        af[mf*2+0] = *(const short8*)&As[d][arow + ((s)*4+mf)*1024 + sl0]; \
        af[mf*2+1] = *(const short8*)&As[d][arow + ((s)*4+mf)*1024 + sl1]; \
    } } while (0)
#define RD_BF(dst, d, s) do { \
    _Pragma("unroll") \
    for (int nf = 0; nf < 2; nf++) { \
        dst[nf*2+0] = *(const short8*)&Bs[d][brow + ((s)*2+nf)*1024 + sl0]; \
        dst[nf*2+1] = *(const short8*)&Bs[d][brow + ((s)*2+nf)*1024 + sl1]; \
    } } while (0)

#define QPH(MB, NB, BF) do { \
    _Pragma("unroll") \
    for (int kk = 0; kk < 2; kk++) \
        _Pragma("unroll") \
        for (int mf = 0; mf < 4; mf++) \
            _Pragma("unroll") \
            for (int nf = 0; nf < 2; nf++) \
                acc[(MB)+mf][(NB)+nf] = __builtin_amdgcn_mfma_f32_16x16x32_bf16(af[mf*2+kk], BF[nf*2+kk], acc[(MB)+mf][(NB)+nf], 0, 0, 0); \
    } while (0)

#define PH_TAIL(MB, NB, BF) do { \
    __builtin_amdgcn_s_barrier(); \
    asm volatile("s_waitcnt lgkmcnt(0)"); \
    __builtin_amdgcn_sched_barrier(0); \
    __builtin_amdgcn_s_setprio(1); \
    QPH(MB, NB, BF); \
    __builtin_amdgcn_s_setprio(0); \
    __builtin_amdgcn_s_barrier(); \
} while (0)

    const int nit = K >> 7;                  // K / 128 (>= 2 for all our shapes)

    STAGE_B(0, 0, 0); STAGE_B(0, 1, 0); STAGE_A(0, 0, 0); STAGE_A(0, 1, 0);
    STAGE_B(1, 0, 1); STAGE_B(1, 1, 1);
    asm volatile("s_waitcnt vmcnt(4)" ::: "memory");   // buf0 resident
    __builtin_amdgcn_s_barrier();

    for (int it = 0; it < nit; ++it) {
        const int kt0 = it*2, kt1 = it*2 + 1;
        const bool more = (it + 1 < nit);
        // ---- P1: reads A0,B0 (buf0); stage A-h0 -> buf1(kt1); MFMA Q00(T0)
        RD_AF(0, 0); RD_BF(bf0, 0, 0);
        STAGE_A(1, 0, kt1);
        PH_TAIL(0, 0, bf0);
        // ---- P2: reads B1 (buf0); stage A-h1 -> buf1(kt1); MFMA Q01(T0)
        RD_BF(bf1, 0, 1);
        STAGE_A(1, 1, kt1);
        PH_TAIL(0, 2, bf1);
        // ---- P3: reads A1 (buf0); stage B-h0 -> buf0(kt0+2); MFMA Q11(T0)
        RD_AF(0, 1);
        if (more) STAGE_B(0, 0, kt0 + 2);
        PH_TAIL(4, 2, bf1);
        // ---- P4: stage B-h1 -> buf0(kt0+2); vmcnt publishes buf1(kt1); MFMA Q10(T0)
        if (more) {
            STAGE_B(0, 1, kt0 + 2);
            asm volatile("s_waitcnt vmcnt(4)" ::: "memory");
        } else {
            asm volatile("s_waitcnt vmcnt(0)" ::: "memory");
        }
        PH_TAIL(4, 0, bf0);
        // ---- P5: reads A0,B0 (buf1); stage A-h0 -> buf0(kt0+2); MFMA Q00(T1)
        RD_AF(1, 0); RD_BF(bf0, 1, 0);
        if (more) STAGE_A(0, 0, kt0 + 2);
        PH_TAIL(0, 0, bf0);
        // ---- P6: reads B1 (buf1); stage A-h1 -> buf0(kt0+2); MFMA Q01(T1)
        RD_BF(bf1, 1, 1);
        if (more) STAGE_A(0, 1, kt0 + 2);
        PH_TAIL(0, 2, bf1);
        // ---- P7: reads A1 (buf1); stage B-h0 -> buf1(kt1+2); MFMA Q11(T1)
        RD_AF(1, 1);
        if (more) STAGE_B(1, 0, kt1 + 2);
        PH_TAIL(4, 2, bf1);
        // ---- P8: stage B-h1 -> buf1(kt1+2); vmcnt publishes buf0(kt0+2); MFMA Q10(T1)
        if (more) {
            STAGE_B(1, 1, kt1 + 2);
            asm volatile("s_waitcnt vmcnt(4)" ::: "memory");
        }
        PH_TAIL(4, 0, bf0);
    }

    // epilogue: C/D layout row = quad*4 + r, col = l15 (verified)
    #pragma unroll
    for (int nf = 0; nf < 4; nf++) {
        const int col = n0 + wn + nf*16 + l15;
        const float bv = bias[col];
        #pragma unroll
        for (int mf = 0; mf < 8; mf++) {
            #pragma unroll
            for (int r = 0; r < 4; r++) {
                const int row = m0 + wm + mf*16 + quad*4 + r;
                float v = acc[mf][nf][r] + bv;
                if (EPI == 0) {
                    // tanh-form gelu via rcp (|err| < 3e-3; e=inf -> th=1, e=0 -> th=-1)
                    float u = 0.7978845608f * (v + 0.044715f * v * v * v);
                    float e = __expf(2.0f * u);
                    float th = 1.0f - 2.0f * __builtin_amdgcn_rcpf(e + 1.0f);
                    float gl = 0.5f * v * (1.0f + th);
                    ((__hip_bfloat16*)Cout)[(size_t)row*N + col] = __float2bfloat16(gl);
                } else {
                    ((float*)Cout)[(size_t)row*N + col] += v;
                }
            }
        }
    }
#undef STAGE_A
#undef STAGE_B
#undef RD_AF
#undef RD_BF
#undef QPH
#undef PH_TAIL
}

extern "C" void kernel_launch(void* const* d_in, const int* in_sizes, int n_in,
                              void* d_out, int out_size, void* d_ws, size_t ws_size,
                              hipStream_t stream) {
    const float* x   = (const float*)d_in[0];
    const float* Wq  = (const float*)d_in[1];
    const float* Wk  = (const float*)d_in[2];
    const float* Wv  = (const float*)d_in[3];
    const float* E   = (const float*)d_in[4];
    const float* Fm  = (const float*)d_in[5];
    const float* Wo  = (const float*)d_in[6];
    const float* bo  = (const float*)d_in[7];
    const float* g1  = (const float*)d_in[8];
    const float* be1 = (const float*)d_in[9];
    const float* g2  = (const float*)d_in[10];
    const float* be2 = (const float*)d_in[11];
    const float* W1  = (const float*)d_in[12];
    const float* bb1 = (const float*)d_in[13];
    const float* W2  = (const float*)d_in[14];
    const float* bb2 = (const float*)d_in[15];
    float* outp = (float*)d_out;

    char* ws = (char*)d_ws;
    size_t o = 0;
    auto alloc = [&](size_t bytes) -> char* {
        char* r = ws + o;
        o = (o + bytes + 255) & ~(size_t)255;
        return r;
    };
    float* xnsum = (float*)alloc((size_t)BATCH*DIMD*4);
    float* Esum  = (float*)alloc(KPROJ*4);
    float* Fsum  = (float*)alloc(KPROJ*4);
    float* stats = (float*)alloc((size_t)NTOK*2*4);
    float* Ksum  = (float*)alloc((size_t)BATCH*DIMD*4);
    float* Vsum  = (float*)alloc((size_t)BATCH*DIMD*4);
    float* Mt    = (float*)alloc((size_t)BATCH*NHEADS*DIMD*4);
    float* P     = (float*)alloc((size_t)BATCH*NHEADS*DIMD*4);
    __hip_bfloat16* xn2  = (__hip_bfloat16*)alloc((size_t)NTOK*DIMD*2);
    __hip_bfloat16* W1T  = (__hip_bfloat16*)alloc((size_t)DIMD*MLPD*2);
    __hip_bfloat16* W2T  = (__hip_bfloat16*)alloc((size_t)MLPD*DIMD*2);
    __hip_bfloat16* hbuf = (__hip_bfloat16*)alloc((size_t)NTOK*MLPD*2);

    hipMemsetAsync(xnsum, 0, (size_t)BATCH*DIMD*4, stream);
    hipMemsetAsync(Esum, 0, KPROJ*4, stream);
    hipMemsetAsync(Fsum, 0, KPROJ*4, stream);
    hipMemsetAsync(Ksum, 0, (size_t)BATCH*DIMD*4, stream);
    hipMemsetAsync(Vsum, 0, (size_t)BATCH*DIMD*4, stream);

    k_ln1sum<<<dim3(BATCH*128), dim3(256), 0, stream>>>(x, g1, be1, stats, xnsum);
    k_efsum<<<dim3(256), dim3(256), 0, stream>>>(E, Fm, Esum, Fsum);
    k_kvsum<<<dim3(512), dim3(256), 0, stream>>>(xnsum, Wk, Wv, Ksum, Vsum);
    k_mt<<<dim3(128), dim3(256), 0, stream>>>(Wq, Ksum, Mt);
    k_p<<<dim3(256), dim3(256), 0, stream>>>(Wo, Vsum, P);
    k_attn_apply<<<dim3(NTOK/TPB), dim3(256), 0, stream>>>(
        x, stats, Mt, P, Esum, Fsum, g1, be1, bo, g2, be2, outp, xn2);
    // W1: [K=1024][N=4096] -> W1T [4096][1024]; W2: [4096][1024] -> W2T [1024][4096]
    k_transpose_bf16<<<dim3(MLPD/32, DIMD/32), dim3(256), 0, stream>>>(W1, W1T, DIMD, MLPD);
    k_transpose_bf16<<<dim3(DIMD/32, MLPD/32), dim3(256), 0, stream>>>(W2, W2T, MLPD, DIMD);
    // GEMM1: h = gelu(xn2 @ W1 + b1)   M=16384 N=4096 K=1024  (64x16 = 1024 blocks)
    k_gemm256<0><<<dim3((NTOK/256)*(MLPD/256)), dim3(512), 0, stream>>>(
        xn2, W1T, bb1, (void*)hbuf, NTOK, MLPD, DIMD);
    // GEMM2: out = y + h @ W2 + b2     M=16384 N=1024 K=4096  (64x4 = 256 blocks)
    k_gemm256<1><<<dim3((NTOK/256)*(DIMD/256)), dim3(512), 0, stream>>>(
        hbuf, W2T, bb2, (void*)outp, NTOK, DIMD, MLPD);
}